// Round 7
// baseline (2573.749 us; speedup 1.0000x reference)
//
#include <hip/hip_runtime.h>
#include <stdint.h>

#define NB 16
#define NS 256
#define NV 32000
#define NE 512
#define NH 1024
#define PAD_IDX 3

// workspace byte offsets
#define WS_XP    0L                 // f32 [4096][1024]   16,777,216 B
#define WS_HCH   16777216L          // bf16 [257][16][1024] 8,421,376 B
#define WS_WHO   25198592L          // bf16 [32000][1024] 65,536,000 B
#define WS_FLG   90734592L          // u32 [257][64]          65,792 B
#define WS_NEED  90800384L

typedef __attribute__((ext_vector_type(8))) short bf16x8;
typedef __attribute__((ext_vector_type(4))) float f32x4;
typedef __attribute__((ext_vector_type(4))) uint32_t u32x4;

__device__ __forceinline__ uint16_t f2bf(float f){
  union { float f; uint32_t u; } v; v.f = f;
  return (uint16_t)((v.u + 0x7fffu + ((v.u >> 16) & 1u)) >> 16);  // RNE
}

__device__ __forceinline__ bf16x8 pack8(float4 a, float4 b){
  bf16x8 r;
  r[0]=(short)f2bf(a.x); r[1]=(short)f2bf(a.y); r[2]=(short)f2bf(a.z); r[3]=(short)f2bf(a.w);
  r[4]=(short)f2bf(b.x); r[5]=(short)f2bf(b.y); r[6]=(short)f2bf(b.z); r[7]=(short)f2bf(b.w);
  return r;
}

// L3-coherent (device-scope) ops: bypass L1+L2
__device__ __forceinline__ u32x4 load_coh16(const void* p){
  u32x4 r;
  asm volatile("global_load_dwordx4 %0, %1, off sc0 sc1" : "=v"(r) : "v"(p) : "memory");
  return r;
}
// L2-scope load: bypass L1 only; hits same-XCD L2 (fast path when producers co-located)
__device__ __forceinline__ u32x4 load_l2_16(const void* p){
  u32x4 r;
  asm volatile("global_load_dwordx4 %0, %1, off sc0" : "=v"(r) : "v"(p) : "memory");
  return r;
}
__device__ __forceinline__ uint32_t load_coh4(const void* p){
  uint32_t r;
  asm volatile("global_load_dword %0, %1, off sc0 sc1" : "=v"(r) : "v"(p) : "memory");
  return r;
}
__device__ __forceinline__ void store_coh8(void* p, uint64_t v){
  asm volatile("global_store_dwordx2 %0, %1, off sc0 sc1" :: "v"(p), "v"(v) : "memory");
}
__device__ __forceinline__ void store_coh4(void* p, uint32_t v){
  asm volatile("global_store_dword %0, %1, off sc0 sc1" :: "v"(p), "v"(v) : "memory");
}

__device__ __forceinline__ void gload_lds16(const void* g, void* l){
  __builtin_amdgcn_global_load_lds(
      (const __attribute__((address_space(1))) uint32_t*)g,
      (__attribute__((address_space(3))) uint32_t*)l, 16, 0, 0);
}

__device__ __forceinline__ u32x4 umax4(u32x4 a, u32x4 b){
  u32x4 r;
  r[0] = a[0] > b[0] ? a[0] : b[0];
  r[1] = a[1] > b[1] ? a[1] : b[1];
  r[2] = a[2] > b[2] ? a[2] : b[2];
  r[3] = a[3] > b[3] ? a[3] : b[3];
  return r;
}

// clamped fast tanh: (e^{2x}-1)/(e^{2x}+1) via exp2; abs err ~1e-5, never NaN/inf
__device__ __forceinline__ float tanh_fast(float x){
  x = fminf(fmaxf(x, -10.f), 10.f);
  float t = __builtin_amdgcn_exp2f(x * 2.885390081777927f);  // 2*log2(e)
  return (t - 1.0f) * __builtin_amdgcn_rcpf(t + 1.0f);
}

// ---- K0: sentinel-fill hchain slots 1..256, hidden -> slot 0, zero done flags
__global__ void k_init(const float* __restrict__ hidden, uint16_t* __restrict__ hch,
                       uint32_t* __restrict__ done){
  long idx = (long)blockIdx.x * 256 + threadIdx.x;   // grid 2048*256 = 524,288
  ((u32x4*)(hch + (long)NB * NH))[idx] = (u32x4){~0u, ~0u, ~0u, ~0u};
  if (idx < NB * NH) hch[idx] = f2bf(hidden[idx]);
  if (idx < 257 * 64) done[idx] = 0u;
}

// ---- K1: Who_w f32 -> bf16 (row-major [32000][1024])
__global__ void k_cvt(const float* __restrict__ src, uint32_t* __restrict__ dst){
  long idx = (long)blockIdx.x * 256 + threadIdx.x;  // 4,096,000 threads, 8 f32 each
  const float4* p = (const float4*)src;
  float4 a = p[idx*2], b = p[idx*2+1];
  u32x4 d;
  d[0] = (uint32_t)f2bf(a.x) | ((uint32_t)f2bf(a.y) << 16);
  d[1] = (uint32_t)f2bf(a.z) | ((uint32_t)f2bf(a.w) << 16);
  d[2] = (uint32_t)f2bf(b.x) | ((uint32_t)f2bf(b.y) << 16);
  d[3] = (uint32_t)f2bf(b.z) | ((uint32_t)f2bf(b.w) << 16);
  ((u32x4*)dst)[idx] = d;
}

// ---- K2: xp[m][n] = sum_k emb(ids[m])[k] * Wxh[n][k] + b[n]   (m=(b,s), bf16 MFMA)
__global__ __launch_bounds__(256) void k_xproj(
    const int* __restrict__ ids, const float* __restrict__ tab,
    const float* __restrict__ wxh, const float* __restrict__ bxh,
    float* __restrict__ xp){
  int bid = blockIdx.x;                 // 64 M-tiles x 16 N-tiles
  int tm = bid & 63, tn = bid >> 6;
  int Mb = tm * 64, Nb = tn * 64;
  int tid = threadIdx.x;
  int w = tid >> 6, l = tid & 63;
  int lr = l & 15, lk = l >> 4;

  int m = Mb + w*16 + lr;
  int id = ids[m];
  const float* arow = tab + (long)id * NE;
  bool pad = (id == PAD_IDX);

  f32x4 acc[4];
  #pragma unroll
  for (int j = 0; j < 4; ++j) acc[j] = (f32x4){0.f,0.f,0.f,0.f};

  for (int k0 = 0; k0 < NE; k0 += 32){
    int k = k0 + lk*8;
    bf16x8 af = (bf16x8){0,0,0,0,0,0,0,0};
    if (!pad){
      float4 a = *(const float4*)(arow + k);
      float4 b = *(const float4*)(arow + k + 4);
      af = pack8(a, b);
    }
    #pragma unroll
    for (int j = 0; j < 4; ++j){
      const float* brow = wxh + (long)(Nb + j*16 + lr) * NE + k;
      float4 x = *(const float4*)brow;
      float4 y = *(const float4*)(brow + 4);
      bf16x8 bf_ = pack8(x, y);
      acc[j] = __builtin_amdgcn_mfma_f32_16x16x32_bf16(af, bf_, acc[j], 0, 0, 0);
    }
  }
  #pragma unroll
  for (int j = 0; j < 4; ++j){
    int n = Nb + j*16 + lr;
    float bias = bxh[n];
    #pragma unroll
    for (int r = 0; r < 4; ++r){
      int row = Mb + w*16 + lk*4 + r;
      xp[(long)row * NH + n] = acc[j][r] + bias;
    }
  }
}

// ---- K3 fused.
// RNN roles: bids {0,8,...,504} (bid%8==0, bid<512) -> all on ONE XCD under the
//   bid%8 round-robin model; 1 wave each; block owns 16 hidden cols. Sentinel
//   data-polling with sc0-only (local-L2) loads, every 4th retry sc0sc1 (L3
//   ground truth -> no stale-line deadlock even if the XCD model is wrong).
//   Producer: fire-and-forget sc0sc1 write-through store; done[t] flag folded
//   into the first vmcnt(0) of step t's poll (certifies slot-t slice at L3).
// GEMM: remaining 8000 blocks, s-major M-tiles (m=s*16+b), tile tm spans 8
//   steps, gated on done[tm*8+8][0..63]; m97-style global_load_lds staging.
__global__ __launch_bounds__(256, 2) void k_fused(
    const float* __restrict__ whh, const float* __restrict__ xp,
    uint16_t* __restrict__ hch, const uint16_t* __restrict__ whobf,
    const float* __restrict__ whob, uint32_t* __restrict__ done,
    float* __restrict__ out, float* __restrict__ hfin){
  __shared__ __align__(16) char smem[32*1024 + 1024];
  const int bid = blockIdx.x;
  const int tid = threadIdx.x;
  const bool isRnn = (bid < 512) && ((bid & 7) == 0);

  if (isRnn){
    // ================= RNN path (1 wave) =================
    if (tid >= 64) return;
    uint16_t* whh_s = (uint16_t*)smem;                 // 32 KB, xor-swizzled
    uint16_t* hs2   = (uint16_t*)(smem + 32*1024);     // [2][256] double buffer
    const int role = bid >> 3;      // 0..63
    const int l    = tid;
    const int j0   = role * 16;
    const int lr = l & 15, lk = l >> 4;

    // stage Whh rows [j0, j0+16) as bf16, swizzle chunk c -> c^(row&7)
    for (int it = 0; it < 32; ++it){
      int chunk = it*64 + l;        // 0..2047 = row*128 + c
      int row = chunk >> 7, c = chunk & 127;
      const float* s0 = whh + (long)(j0 + row) * NH + c*8;
      float4 a = *(const float4*)s0;
      float4 b = *(const float4*)(s0 + 4);
      u32x4 d;
      d[0] = (uint32_t)f2bf(a.x) | ((uint32_t)f2bf(a.y) << 16);
      d[1] = (uint32_t)f2bf(a.z) | ((uint32_t)f2bf(a.w) << 16);
      d[2] = (uint32_t)f2bf(b.x) | ((uint32_t)f2bf(b.y) << 16);
      d[3] = (uint32_t)f2bf(b.z) | ((uint32_t)f2bf(b.w) << 16);
      ((u32x4*)whh_s)[row*128 + (c ^ (row & 7))] = d;
    }
    asm volatile("s_waitcnt lgkmcnt(0)" ::: "memory");
    __builtin_amdgcn_sched_barrier(0);

    float xpreg[4];
    #pragma unroll
    for (int r = 0; r < 4; ++r)
      xpreg[r] = xp[((long)(lk*4 + r) * NS + 0) * NH + j0 + lr];

    const char* hbase = (const char*)hch;
    for (int t = 0; t < NS; ++t){
      const char* hsrc = hbase + (long)t * NB * NH * 2 + lr * 2048 + lk * 16;
      u32x4 hfrag[32];
      bool first = true;
      int iter = 0;
      while (true){
        if ((iter & 3) != 3){
          #pragma unroll
          for (int kk = 0; kk < 32; ++kk) hfrag[kk] = load_l2_16(hsrc + kk * 64);
        } else {
          #pragma unroll
          for (int kk = 0; kk < 32; ++kk) hfrag[kk] = load_coh16(hsrc + kk * 64);
        }
        asm volatile("s_waitcnt vmcnt(0)" ::: "memory");
        __builtin_amdgcn_sched_barrier(0);   // pin check AFTER waitcnt (rule #18)
        if (first){
          if (l == 0 && t > 0) store_coh4(done + t*64 + role, 1u);  // slot-t slice acked
          first = false;
        }
        u32x4 m4 = hfrag[0];
        #pragma unroll
        for (int kk = 1; kk < 32; ++kk) m4 = umax4(m4, hfrag[kk]);
        uint32_t m01 = m4[0] > m4[1] ? m4[0] : m4[1];
        uint32_t m23 = m4[2] > m4[3] ? m4[2] : m4[3];
        uint32_t m = m01 > m23 ? m01 : m23;
        if (__all(m != 0xFFFFFFFFu)) break;
        ++iter;
      }
      __builtin_amdgcn_sched_barrier(0);

      f32x4 a0 = (f32x4){0.f,0.f,0.f,0.f}, a1 = a0, a2 = a0, a3 = a0;
      #pragma unroll
      for (int kk = 0; kk < 32; kk += 4){
        int c0 = kk*4 + lk;
        bf16x8 b0 = *(const bf16x8*)&((const u32x4*)whh_s)[lr*128 + ( c0      ^ (lr & 7))];
        bf16x8 b1 = *(const bf16x8*)&((const u32x4*)whh_s)[lr*128 + ((c0 + 4) ^ (lr & 7))];
        bf16x8 b2 = *(const bf16x8*)&((const u32x4*)whh_s)[lr*128 + ((c0 + 8) ^ (lr & 7))];
        bf16x8 b3 = *(const bf16x8*)&((const u32x4*)whh_s)[lr*128 + ((c0 +12) ^ (lr & 7))];
        a0 = __builtin_amdgcn_mfma_f32_16x16x32_bf16(*(const bf16x8*)&hfrag[kk  ], b0, a0, 0, 0, 0);
        a1 = __builtin_amdgcn_mfma_f32_16x16x32_bf16(*(const bf16x8*)&hfrag[kk+1], b1, a1, 0, 0, 0);
        a2 = __builtin_amdgcn_mfma_f32_16x16x32_bf16(*(const bf16x8*)&hfrag[kk+2], b2, a2, 0, 0, 0);
        a3 = __builtin_amdgcn_mfma_f32_16x16x32_bf16(*(const bf16x8*)&hfrag[kk+3], b3, a3, 0, 0, 0);
      }
      f32x4 acc = (a0 + a1) + (a2 + a3);

      uint16_t* hb = hs2 + (t & 1)*256;
      #pragma unroll
      for (int r = 0; r < 4; ++r){
        int b = lk*4 + r;                           // C/D: row=(l>>4)*4+r, col=l&15
        float hv = tanh_fast(xpreg[r] + acc[r]);
        hb[b*16 + lr] = f2bf(hv);
        if (t == NS-1) hfin[b*NH + j0 + lr] = hv;
      }
      asm volatile("s_waitcnt lgkmcnt(0)" ::: "memory");
      __builtin_amdgcn_sched_barrier(0);

      {  // coalesced write-through store of slot t+1 slice (fire-and-forget)
        int rb = l >> 2, cc = l & 3;
        uint32_t w0 = *(const uint32_t*)&hb[rb*16 + cc*4];
        uint32_t w1 = *(const uint32_t*)&hb[rb*16 + cc*4 + 2];
        char* dst = (char*)hch + (long)(t+1) * NB * NH * 2 + rb * 2048 + j0*2 + cc*8;
        store_coh8(dst, ((uint64_t)w1 << 32) | (uint64_t)w0);
      }

      if (t + 1 < NS){
        #pragma unroll
        for (int r = 0; r < 4; ++r)
          xpreg[r] = xp[((long)(lk*4 + r) * NS + (t+1)) * NH + j0 + lr];
      }
    }
    asm volatile("s_waitcnt vmcnt(0)" ::: "memory");
    if (l == 0) store_coh4(done + NS*64 + role, 1u);
    return;
  }

  // ================= logits path (s-major tiles, gload_lds staging) ==========
  uint16_t* As = (uint16_t*)smem;          // [128][32] bf16 linear, 8 KB
  uint16_t* Bs = (uint16_t*)(smem + 8192); // [128][32] bf16 linear, 8 KB
  int tile = (bid < 512) ? (bid - ((bid + 7) >> 3)) : (bid - 64);  // 0..7999
  int tm = tile / 250;                     // s-group (8 steps per tile)
  int tn = tile % 250;
  int Mb = tm * 128, Nb = tn * 128;
  int hs = tm * 8 + 8;                     // highest needed slot

  // flag gate: 64 B poll of done[hs][0..63]
  {
    const uint32_t* gp = done + hs*64 + (tid & 63);
    while (true){
      uint32_t f = load_coh4(gp);
      asm volatile("s_waitcnt vmcnt(0)" ::: "memory");
      __builtin_amdgcn_sched_barrier(0);
      if (__syncthreads_count(f == 0u) == 0) break;
      __builtin_amdgcn_s_sleep(16);
    }
  }

  int wv = tid >> 6, l = tid & 63;
  int wm = wv >> 1, wn = wv & 1;
  int lr = l & 15, lk = l >> 4;

  // staging coords: thread -> (row r=tid>>2, chunk c=tid&3); linear LDS = tid*8 elems
  int r = tid >> 2, c = tid & 3;
  const uint16_t* ga0 = hch + (long)(Mb + 16 + r) * NH + c*8;     // rows 0..63
  const uint16_t* ga1 = ga0 + (long)64 * NH;                      // rows 64..127
  const uint16_t* gb0 = whobf + (long)(Nb + r) * NH + c*8;
  const uint16_t* gb1 = gb0 + (long)64 * NH;
  uint16_t* lA = As + wv*512;              // wave-uniform base; HW adds lane*16B
  uint16_t* lB = Bs + wv*512;

  f32x4 acc[4][4];
  #pragma unroll
  for (int i = 0; i < 4; ++i)
    #pragma unroll
    for (int j = 0; j < 4; ++j) acc[i][j] = (f32x4){0.f,0.f,0.f,0.f};

  for (int kt = 0; kt < 32; ++kt){
    __syncthreads();                       // prev-iter LDS reads done
    int off = kt * 32;
    gload_lds16(ga0 + off, lA);
    gload_lds16(ga1 + off, lA + 2048);
    gload_lds16(gb0 + off, lB);
    gload_lds16(gb1 + off, lB + 2048);
    asm volatile("s_waitcnt vmcnt(0)" ::: "memory");
    __syncthreads();

    bf16x8 af[4], bg_[4];
    #pragma unroll
    for (int i = 0; i < 4; ++i){
      int ra = wm*64 + i*16 + lr;
      int rb = wn*64 + i*16 + lr;
      af[i]  = *(const bf16x8*)&((const u32x4*)As)[ra*4 + lk];
      bg_[i] = *(const bf16x8*)&((const u32x4*)Bs)[rb*4 + lk];
    }
    #pragma unroll
    for (int i = 0; i < 4; ++i)
      #pragma unroll
      for (int j = 0; j < 4; ++j)
        acc[i][j] = __builtin_amdgcn_mfma_f32_16x16x32_bf16(af[i], bg_[j], acc[i][j], 0, 0, 0);
  }

  #pragma unroll
  for (int j = 0; j < 4; ++j){
    int col = Nb + wn*64 + j*16 + lr;
    float bias = whob[col];
    #pragma unroll
    for (int i = 0; i < 4; ++i){
      #pragma unroll
      for (int rr = 0; rr < 4; ++rr){
        int m = Mb + wm*64 + i*16 + lk*4 + rr;      // m = s*16 + b
        long orow = (long)((m & 15) * 256 + (m >> 4));
        out[orow * NV + col] = acc[i][j][rr] + bias;
      }
    }
  }
}

extern "C" void kernel_launch(void* const* d_in, const int* in_sizes, int n_in,
                              void* d_out, int out_size, void* d_ws, size_t ws_size,
                              hipStream_t stream){
  (void)in_sizes; (void)n_in; (void)out_size;
  if (ws_size < (size_t)WS_NEED) return;   // insufficient scratch -> fail loudly (poison stays)

  const int*   ids    = (const int*)  d_in[0];
  const float* hidden = (const float*)d_in[1];
  const float* table  = (const float*)d_in[2];
  const float* wxh    = (const float*)d_in[3];
  const float* bxh    = (const float*)d_in[4];
  const float* whh    = (const float*)d_in[5];
  const float* who    = (const float*)d_in[6];
  const float* whob   = (const float*)d_in[7];

  char* ws = (char*)d_ws;
  float*    xp     = (float*)   (ws + WS_XP);
  uint16_t* hchain = (uint16_t*)(ws + WS_HCH);
  uint16_t* whobf  = (uint16_t*)(ws + WS_WHO);
  uint32_t* done   = (uint32_t*)(ws + WS_FLG);
  float* out    = (float*)d_out;
  float* hfinal = out + (long)NB * NS * NV;   // 131,072,000

  k_init <<<2048,  256, 0, stream>>>(hidden, hchain, done);
  k_cvt  <<<16000, 256, 0, stream>>>(who, (uint32_t*)whobf);
  k_xproj<<<1024,  256, 0, stream>>>(ids, table, wxh, bxh, xp);
  k_fused<<<8064,  256, 0, stream>>>(whh, xp, hchain, whobf, whob, done, out, hfinal);
}

// Round 8
// 2306.676 us; speedup vs baseline: 1.1158x; 1.1158x over previous
//
#include <hip/hip_runtime.h>
#include <stdint.h>

#define NB 16
#define NS 256
#define NV 32000
#define NE 512
#define NH 1024
#define PAD_IDX 3

// workspace byte offsets
#define WS_XP    0L                 // f32 [4096][1024]   16,777,216 B
#define WS_HCH   16777216L          // bf16 [257][16][1024] 8,421,376 B
#define WS_WHO   25198592L          // bf16 [32000][1024] 65,536,000 B
#define WS_FLG   90734592L          // u32 done2[257][4] + done3[256]
#define WS_NEED  90800384L

typedef __attribute__((ext_vector_type(8))) short bf16x8;
typedef __attribute__((ext_vector_type(4))) float f32x4;
typedef __attribute__((ext_vector_type(4))) uint32_t u32x4;

__device__ __forceinline__ uint16_t f2bf(float f){
  union { float f; uint32_t u; } v; v.f = f;
  return (uint16_t)((v.u + 0x7fffu + ((v.u >> 16) & 1u)) >> 16);  // RNE
}

__device__ __forceinline__ bf16x8 pack8(float4 a, float4 b){
  bf16x8 r;
  r[0]=(short)f2bf(a.x); r[1]=(short)f2bf(a.y); r[2]=(short)f2bf(a.z); r[3]=(short)f2bf(a.w);
  r[4]=(short)f2bf(b.x); r[5]=(short)f2bf(b.y); r[6]=(short)f2bf(b.z); r[7]=(short)f2bf(b.w);
  return r;
}

// L3-coherent (device-scope) ops: bypass L1+L2
__device__ __forceinline__ u32x4 load_coh16(const void* p){
  u32x4 r;
  asm volatile("global_load_dwordx4 %0, %1, off sc0 sc1" : "=v"(r) : "v"(p) : "memory");
  return r;
}
__device__ __forceinline__ uint32_t load_coh4(const void* p){
  uint32_t r;
  asm volatile("global_load_dword %0, %1, off sc0 sc1" : "=v"(r) : "v"(p) : "memory");
  return r;
}
__device__ __forceinline__ void store_coh4(void* p, uint32_t v){
  asm volatile("global_store_dword %0, %1, off sc0 sc1" :: "v"(p), "v"(v) : "memory");
}

__device__ __forceinline__ u32x4 umax4(u32x4 a, u32x4 b){
  u32x4 r;
  r[0] = a[0] > b[0] ? a[0] : b[0];
  r[1] = a[1] > b[1] ? a[1] : b[1];
  r[2] = a[2] > b[2] ? a[2] : b[2];
  r[3] = a[3] > b[3] ? a[3] : b[3];
  return r;
}

// clamped fast tanh: (e^{2x}-1)/(e^{2x}+1) via exp2; abs err ~1e-5, never NaN/inf
__device__ __forceinline__ float tanh_fast(float x){
  x = fminf(fmaxf(x, -10.f), 10.f);
  float t = __builtin_amdgcn_exp2f(x * 2.885390081777927f);  // 2*log2(e)
  return (t - 1.0f) * __builtin_amdgcn_rcpf(t + 1.0f);
}

// ---- K0: sentinel-fill hchain slots 1..256, hidden -> slot 0, zero flags
__global__ void k_init(const float* __restrict__ hidden, uint16_t* __restrict__ hch,
                       uint32_t* __restrict__ flg){
  long idx = (long)blockIdx.x * 256 + threadIdx.x;   // grid 2048*256 = 524,288
  ((u32x4*)(hch + (long)NB * NH))[idx] = (u32x4){~0u, ~0u, ~0u, ~0u};
  if (idx < NB * NH) hch[idx] = f2bf(hidden[idx]);
  if (idx < 2048) flg[idx] = 0u;
}

// ---- K1: Who_w f32 -> bf16 (row-major [32000][1024])
__global__ void k_cvt(const float* __restrict__ src, uint32_t* __restrict__ dst){
  long idx = (long)blockIdx.x * 256 + threadIdx.x;  // 4,096,000 threads, 8 f32 each
  const float4* p = (const float4*)src;
  float4 a = p[idx*2], b = p[idx*2+1];
  u32x4 d;
  d[0] = (uint32_t)f2bf(a.x) | ((uint32_t)f2bf(a.y) << 16);
  d[1] = (uint32_t)f2bf(a.z) | ((uint32_t)f2bf(a.w) << 16);
  d[2] = (uint32_t)f2bf(b.x) | ((uint32_t)f2bf(b.y) << 16);
  d[3] = (uint32_t)f2bf(b.z) | ((uint32_t)f2bf(b.w) << 16);
  ((u32x4*)dst)[idx] = d;
}

// ---- K2: xp[m][n] = sum_k emb(ids[m])[k] * Wxh[n][k] + b[n]   (m=(b,s), bf16 MFMA)
__global__ __launch_bounds__(256) void k_xproj(
    const int* __restrict__ ids, const float* __restrict__ tab,
    const float* __restrict__ wxh, const float* __restrict__ bxh,
    float* __restrict__ xp){
  int bid = blockIdx.x;                 // 64 M-tiles x 16 N-tiles
  int tm = bid & 63, tn = bid >> 6;
  int Mb = tm * 64, Nb = tn * 64;
  int tid = threadIdx.x;
  int w = tid >> 6, l = tid & 63;
  int lr = l & 15, lk = l >> 4;

  int m = Mb + w*16 + lr;
  int id = ids[m];
  const float* arow = tab + (long)id * NE;
  bool pad = (id == PAD_IDX);

  f32x4 acc[4];
  #pragma unroll
  for (int j = 0; j < 4; ++j) acc[j] = (f32x4){0.f,0.f,0.f,0.f};

  for (int k0 = 0; k0 < NE; k0 += 32){
    int k = k0 + lk*8;
    bf16x8 af = (bf16x8){0,0,0,0,0,0,0,0};
    if (!pad){
      float4 a = *(const float4*)(arow + k);
      float4 b = *(const float4*)(arow + k + 4);
      af = pack8(a, b);
    }
    #pragma unroll
    for (int j = 0; j < 4; ++j){
      const float* brow = wxh + (long)(Nb + j*16 + lr) * NE + k;
      float4 x = *(const float4*)brow;
      float4 y = *(const float4*)(brow + 4);
      bf16x8 bf_ = pack8(x, y);
      acc[j] = __builtin_amdgcn_mfma_f32_16x16x32_bf16(af, bf_, acc[j], 0, 0, 0);
    }
  }
  #pragma unroll
  for (int j = 0; j < 4; ++j){
    int n = Nb + j*16 + lr;
    float bias = bxh[n];
    #pragma unroll
    for (int r = 0; r < 4; ++r){
      int row = Mb + w*16 + lk*4 + r;
      xp[(long)row * NH + n] = acc[j][r] + bias;
    }
  }
}

// ---- K3 fused.
// RNN (bids 0..63): 4 groups x 16 blocks x 4 waves. Group g = batches 4g..4g+3
//   (independent chains per group, sync set = 16 blocks). Wave (g,c,j) owns
//   cols [c*64+j*16, +16): Whh slice lives in 128 VGPR for the whole kernel.
//   Per step: sentinel-poll the 4 batch rows of h_t in 2 halves (masked to
//   lanes lr<4), MFMA each half (M=16, rows 4..15 garbage -> rows don't mix),
//   tanh, publish h_{t+1} via 4B-packed (shfl-pair) write-through stores.
//   Group c0/j0 wave certifies slot t at L3 (its sc0sc1 poll passed) ->
//   done2[t][g]; after the loop every wave acks its slot-256 stores -> done3.
// GEMM (8000 tiles): R6 reg-staged 128x128, s-major M (tile tm spans 8 steps),
//   gated on done2[tm*8+8][g] for all 4 g (or done3[0..255] for the last row).
__global__ __launch_bounds__(256, 2) void k_fused(
    const float* __restrict__ whh, const float* __restrict__ xp,
    uint16_t* __restrict__ hch, const uint16_t* __restrict__ whobf,
    const float* __restrict__ whob, uint32_t* __restrict__ done2,
    uint32_t* __restrict__ done3, float* __restrict__ out,
    float* __restrict__ hfin){
  __shared__ __align__(16) char smem[16*1024 + 1024];
  const int bid = blockIdx.x;
  const int tid = threadIdx.x;

  if (bid < 64){
    // ================= RNN path =================
    const int g = bid >> 4, c = bid & 15;
    const int j = tid >> 6, l = tid & 63;
    const int lr = l & 15, lk = l >> 4;
    const int ncol = c*64 + j*16 + lr;
    __builtin_amdgcn_s_setprio(2);

    // Whh slice -> registers (32 x bf16x8 = 128 VGPR), row ncol, all K
    bf16x8 wf[32];
    #pragma unroll
    for (int kk = 0; kk < 32; ++kk){
      const float* s0 = whh + (long)ncol * NH + kk*32 + lk*8;
      wf[kk] = pack8(*(const float4*)s0, *(const float4*)(s0 + 4));
    }

    float xpreg[4];
    if (l < 16){
      #pragma unroll
      for (int r = 0; r < 4; ++r)
        xpreg[r] = xp[((long)(4*g + r) * NS + 0) * NH + ncol];
    }

    const char* hbase = (const char*)hch;
    u32x4 ha[16];
    #pragma unroll
    for (int q = 0; q < 16; ++q) ha[q] = (u32x4){0u,0u,0u,0u};

    for (int t = 0; t < NS; ++t){
      // A rows = batches 4g..4g+3 (lanes lr<4 active); frag kk at byte kk*64+lk*16
      const char* hrow = hbase + ((long)t * NB + 4*g + (lr & 3)) * NH * 2 + lk * 16;
      f32x4 acc = (f32x4){0.f,0.f,0.f,0.f};

      #pragma unroll
      for (int half = 0; half < 2; ++half){
        while (true){
          if (lr < 4){
            #pragma unroll
            for (int q = 0; q < 16; ++q)
              ha[q] = load_coh16(hrow + (half*16 + q) * 64);
          }
          asm volatile("s_waitcnt vmcnt(0)" ::: "memory");
          __builtin_amdgcn_sched_barrier(0);   // pin check AFTER waitcnt (rule #18)
          u32x4 m4 = ha[0];
          #pragma unroll
          for (int q = 1; q < 16; ++q) m4 = umax4(m4, ha[q]);
          uint32_t m01 = m4[0] > m4[1] ? m4[0] : m4[1];
          uint32_t m23 = m4[2] > m4[3] ? m4[2] : m4[3];
          uint32_t mm = m01 > m23 ? m01 : m23;
          if (__all(lr >= 4 || mm != 0xFFFFFFFFu)) break;
        }
        __builtin_amdgcn_sched_barrier(0);
        #pragma unroll
        for (int q = 0; q < 16; ++q)
          acc = __builtin_amdgcn_mfma_f32_16x16x32_bf16(
                  *(const bf16x8*)&ha[q], wf[half*16 + q], acc, 0, 0, 0);
      }

      // slot t fully verified at L3 by this wave's sc0sc1 polls -> certify
      if (c == 0 && j == 0 && l == 0) store_coh4(done2 + t*4 + g, 1u);

      // epilogue: lanes 0..15 hold C rows 0..3 (batches) for col ncol
      if (l < 16){
        #pragma unroll
        for (int r = 0; r < 4; ++r){
          float hv = tanh_fast(xpreg[r] + acc[r]);
          if (t == NS-1) hfin[(long)(4*g + r) * NH + ncol] = hv;
          uint32_t hb = (uint32_t)f2bf(hv);
          uint32_t ob = (uint32_t)__shfl_xor((int)hb, 1);
          if ((l & 1) == 0){
            uint32_t w32 = hb | (ob << 16);     // cols (ncol, ncol+1) packed
            char* dst = (char*)hch + (((long)(t+1) * NB + 4*g + r) * NH + ncol) * 2;
            store_coh4(dst, w32);               // 4B atomic unit: no tearing
          }
        }
        if (t + 1 < NS){
          #pragma unroll
          for (int r = 0; r < 4; ++r)
            xpreg[r] = xp[((long)(4*g + r) * NS + (t+1)) * NH + ncol];
        }
      }
    }
    asm volatile("s_waitcnt vmcnt(0)" ::: "memory");   // ack this wave's slot-256 stores
    if (l == 0) store_coh4(done3 + bid*4 + j, 1u);
    return;
  }

  // ================= logits path (R6 reg-staged engine) =================
  uint16_t* As = (uint16_t*)smem;          // 8 KB
  uint16_t* Bs = (uint16_t*)(smem + 8192); // 8 KB
  int tile = bid - 64;                     // 0..7999
  int tm = tile / 250;                     // s-group (8 steps per tile)
  int tn = tile % 250;
  int Mb = tm * 128, Nb = tn * 128;
  int hs = tm * 8 + 8;                     // highest needed slot

  if (hs < 256){                           // gate: 4 group flags
    const uint32_t* gp = done2 + hs*4 + (tid & 3);
    while (true){
      uint32_t f = load_coh4(gp);
      asm volatile("s_waitcnt vmcnt(0)" ::: "memory");
      __builtin_amdgcn_sched_barrier(0);
      if (__syncthreads_count(f == 0u) == 0) break;
      __builtin_amdgcn_s_sleep(16);
    }
  } else {                                 // last s-row: 256 per-wave finals
    const uint32_t* gp = done3 + tid;
    while (true){
      uint32_t f = load_coh4(gp);
      asm volatile("s_waitcnt vmcnt(0)" ::: "memory");
      __builtin_amdgcn_sched_barrier(0);
      if (__syncthreads_count(f == 0u) == 0) break;
      __builtin_amdgcn_s_sleep(16);
    }
  }

  int wv = tid >> 6, l = tid & 63;
  int wm = wv >> 1, wn = wv & 1;
  int lr = l & 15, lk = l >> 4;

  int r0 = tid >> 2, c0 = tid & 3;
  int r1 = r0 + 64;
  // s-major: A row m <-> hchain row m+16 (contiguous)
  const uint16_t* pa0 = hch + (long)(Mb + r0 + 16) * NH + c0*8;
  const uint16_t* pa1 = hch + (long)(Mb + r1 + 16) * NH + c0*8;
  const uint16_t* pb0 = whobf + (long)(Nb + r0) * NH + c0*8;
  const uint16_t* pb1 = whobf + (long)(Nb + r1) * NH + c0*8;
  int da0 = r0*4 + (c0 ^ (r0 & 3));
  int da1 = r1*4 + (c0 ^ (r1 & 3));

  u32x4 ra0 = *(const u32x4*)pa0;
  u32x4 ra1 = *(const u32x4*)pa1;
  u32x4 rb0 = *(const u32x4*)pb0;
  u32x4 rb1 = *(const u32x4*)pb1;

  f32x4 acc[4][4];
  #pragma unroll
  for (int i = 0; i < 4; ++i)
    #pragma unroll
    for (int jj = 0; jj < 4; ++jj) acc[i][jj] = (f32x4){0.f,0.f,0.f,0.f};

  for (int kt = 0; kt < 32; ++kt){
    ((u32x4*)As)[da0] = ra0;
    ((u32x4*)As)[da1] = ra1;
    ((u32x4*)Bs)[da0] = rb0;
    ((u32x4*)Bs)[da1] = rb1;
    __syncthreads();
    if (kt != 31){
      int off = (kt + 1) * 32;
      ra0 = *(const u32x4*)(pa0 + off);
      ra1 = *(const u32x4*)(pa1 + off);
      rb0 = *(const u32x4*)(pb0 + off);
      rb1 = *(const u32x4*)(pb1 + off);
    }
    bf16x8 af[4], bg_[4];
    #pragma unroll
    for (int i = 0; i < 4; ++i){
      int ra = wm*64 + i*16 + lr;
      int rb = wn*64 + i*16 + lr;
      af[i]  = *(const bf16x8*)&((const u32x4*)As)[ra*4 + (lk ^ (ra & 3))];
      bg_[i] = *(const bf16x8*)&((const u32x4*)Bs)[rb*4 + (lk ^ (rb & 3))];
    }
    #pragma unroll
    for (int i = 0; i < 4; ++i)
      #pragma unroll
      for (int jj = 0; jj < 4; ++jj)
        acc[i][jj] = __builtin_amdgcn_mfma_f32_16x16x32_bf16(af[i], bg_[jj], acc[i][jj], 0, 0, 0);
    __syncthreads();
  }

  #pragma unroll
  for (int jj = 0; jj < 4; ++jj){
    int col = Nb + wn*64 + jj*16 + lr;
    float bias = whob[col];
    #pragma unroll
    for (int i = 0; i < 4; ++i){
      #pragma unroll
      for (int rr = 0; rr < 4; ++rr){
        int m = Mb + wm*64 + i*16 + lk*4 + rr;      // m = s*16 + b
        long orow = (long)((m & 15) * 256 + (m >> 4));
        out[orow * NV + col] = acc[i][jj][rr] + bias;
      }
    }
  }
}

extern "C" void kernel_launch(void* const* d_in, const int* in_sizes, int n_in,
                              void* d_out, int out_size, void* d_ws, size_t ws_size,
                              hipStream_t stream){
  (void)in_sizes; (void)n_in; (void)out_size;
  if (ws_size < (size_t)WS_NEED) return;   // insufficient scratch -> fail loudly (poison stays)

  const int*   ids    = (const int*)  d_in[0];
  const float* hidden = (const float*)d_in[1];
  const float* table  = (const float*)d_in[2];
  const float* wxh    = (const float*)d_in[3];
  const float* bxh    = (const float*)d_in[4];
  const float* whh    = (const float*)d_in[5];
  const float* who    = (const float*)d_in[6];
  const float* whob   = (const float*)d_in[7];

  char* ws = (char*)d_ws;
  float*    xp     = (float*)   (ws + WS_XP);
  uint16_t* hchain = (uint16_t*)(ws + WS_HCH);
  uint16_t* whobf  = (uint16_t*)(ws + WS_WHO);
  uint32_t* done2  = (uint32_t*)(ws + WS_FLG);            // [257][4]
  uint32_t* done3  = done2 + 257*4;                       // [256]
  float* out    = (float*)d_out;
  float* hfinal = out + (long)NB * NS * NV;   // 131,072,000

  k_init <<<2048,  256, 0, stream>>>(hidden, hchain, done2);
  k_cvt  <<<16000, 256, 0, stream>>>(who, (uint32_t*)whobf);
  k_xproj<<<1024,  256, 0, stream>>>(ids, table, wxh, bxh, xp);
  k_fused<<<8064,  256, 0, stream>>>(whh, xp, hchain, whobf, whob,
                                     done2, done3, out, hfinal);
}